// Round 8
// baseline (137.005 us; speedup 1.0000x reference)
//
#include <hip/hip_runtime.h>

// Problem constants (from reference: shape (32,1,512,512) fp32)
#define BATCH 32
#define H 512
#define W 512
#define N_TOT (BATCH * H * W)   // 8388608
#define NSLABS 2048             // 512x8 row-slabs total (64 per batch image)
#define GRID 1024               // each block handles 2 slabs

// Round-8 theory: duration has tracked BLOCK COUNT across all rounds
// (~15 ns/workgroup dispatch): 8192 blk=116us, 4096=78, 2048=47. All pipes
// <25% busy, occupancy << launched -> CP dispatch rate, not memory/VALU, is
// the limiter. Fix: keep round-4's proven per-wave body (84 VGPR, no spill,
// shuffle halo) but process 2 slabs per block (#pragma unroll 1 so the
// register allocator never sees both slabs' loads live -> no round-5-style
// spill), halving dispatches to 1024. Atomics halve too.

__device__ __forceinline__ void sobel_pass(const float* __restrict__ p,
                                           int base, int x0, int y0, int tx,
                                           float sob[2][8])
{
    float h1[4][8], h2[4][8];
#pragma unroll
    for (int rr = 0; rr < 4; ++rr) {
        const int yy = y0 - 1 + rr;
        const bool rv = (unsigned)yy < (unsigned)H;   // wave-uniform
        const float* row = p + base + yy * W + x0;
        float4 s1 = make_float4(0.f, 0.f, 0.f, 0.f), s2 = s1;
        if (rv) {
            s1 = *reinterpret_cast<const float4*>(row);       // cols x0..x0+3
            s2 = *reinterpret_cast<const float4*>(row + 4);   // cols x0+4..x0+7
        }
        float lw = __shfl_up(s2.w, 1, 64);    // lane tx-1's col x0-1
        if (tx == 0)  lw = 0.f;               // image left edge: zero-pad
        float rw = __shfl_down(s1.x, 1, 64);  // lane tx+1's col x0+8
        if (tx == 63) rw = 0.f;               // image right edge: zero-pad
        const float v[10] = {lw, s1.x, s1.y, s1.z, s1.w,
                             s2.x, s2.y, s2.z, s2.w, rw};
#pragma unroll
        for (int c = 0; c < 8; ++c) {
            h1[rr][c] = v[c + 2] - v[c];                    // row conv [-1,0,1]
            h2[rr][c] = v[c] + 2.f * v[c + 1] + v[c + 2];   // row conv [1,2,1]
        }
    }
#pragma unroll
    for (int o = 0; o < 2; ++o)
#pragma unroll
        for (int c = 0; c < 8; ++c) {
            const float gx = h1[o][c] + 2.f * h1[o + 1][c] + h1[o + 2][c];
            const float gy = h2[o][c] - h2[o + 2][c];
            sob[o][c] = fabsf(gx) + fabsf(gy);
        }
}

__global__ __launch_bounds__(256)
void fusion_loss_kernel(const float* __restrict__ A,
                        const float* __restrict__ B,
                        const float* __restrict__ F,
                        const int* __restrict__ scheme_arr,
                        float* __restrict__ out)
{
    __shared__ float red[4];

    const int t   = threadIdx.x;
    const int tx  = t & 63;                  // lane: column group (8 px each)
    const int ty  = t >> 6;                  // wave: row pair 0..3
    const int x0  = tx << 3;

    float acc = 0.f;

#pragma unroll 1   // sequential slabs: keep one slab's loads live at a time
    for (int s = blockIdx.x; s < NSLABS; s += GRID) {
        const int b    = s >> 6;                     // batch image
        const int y0   = ((s & 63) << 3) + (ty << 1);
        const int base = b * (H * W);
        const int scheme = scheme_arr[b];

        // ---- l_loss mini-pass: rows y0,y0+1, own 8 cols (in-bounds) ----
#pragma unroll
        for (int rr = 0; rr < 2; ++rr) {
            const int ro = base + (y0 + rr) * W + x0;
            const float4 a0 = *reinterpret_cast<const float4*>(A + ro);
            const float4 a1 = *reinterpret_cast<const float4*>(A + ro + 4);
            const float4 b0 = *reinterpret_cast<const float4*>(B + ro);
            const float4 b1 = *reinterpret_cast<const float4*>(B + ro + 4);
            const float4 f0 = *reinterpret_cast<const float4*>(F + ro);
            const float4 f1 = *reinterpret_cast<const float4*>(F + ro + 4);
            const float av[8] = {a0.x, a0.y, a0.z, a0.w, a1.x, a1.y, a1.z, a1.w};
            const float bv[8] = {b0.x, b0.y, b0.z, b0.w, b1.x, b1.y, b1.z, b1.w};
            const float fv[8] = {f0.x, f0.y, f0.z, f0.w, f1.x, f1.y, f1.z, f1.w};
#pragma unroll
            for (int c = 0; c < 8; ++c) {
                const float ab = (scheme == 0) ? 0.5f * (av[c] + bv[c])
                               : (scheme == 1) ? fmaxf(av[c], bv[c])
                               : 0.f;
                acc += fabsf(ab - fv[c]);
            }
        }

        // ---- grad_loss: sequential per-image sobel, running max, fold F ----
        float sobM[2][8], sobT[2][8];
        sobel_pass(A, base, x0, y0, tx, sobM);
        sobel_pass(B, base, x0, y0, tx, sobT);
#pragma unroll
        for (int o = 0; o < 2; ++o)
#pragma unroll
            for (int c = 0; c < 8; ++c)
                sobM[o][c] = fmaxf(sobM[o][c], sobT[o][c]);
        sobel_pass(F, base, x0, y0, tx, sobT);
#pragma unroll
        for (int o = 0; o < 2; ++o)
#pragma unroll
            for (int c = 0; c < 8; ++c)
                acc += fabsf(sobT[o][c] - sobM[o][c]);
    }

    // ---- reduction: 64-lane shuffle, cross-wave via LDS, one atomic ----
#pragma unroll
    for (int off = 32; off > 0; off >>= 1)
        acc += __shfl_down(acc, off, 64);
    if ((t & 63) == 0) red[t >> 6] = acc;
    __syncthreads();
    if (t == 0)
        atomicAdd(out, (red[0] + red[1] + red[2] + red[3]) * (1.0f / (float)N_TOT));
}

extern "C" void kernel_launch(void* const* d_in, const int* in_sizes, int n_in,
                              void* d_out, int out_size, void* d_ws, size_t ws_size,
                              hipStream_t stream)
{
    const float* A = (const float*)d_in[0];
    const float* B = (const float*)d_in[1];
    const float* F = (const float*)d_in[2];
    const int* scheme = (const int*)d_in[3];
    float* out = (float*)d_out;

    // d_out is poisoned before every launch; zero it for the atomics.
    hipMemsetAsync(out, 0, sizeof(float), stream);

    dim3 grid(GRID);    // 1024 blocks, 2 slabs each
    dim3 block(256);
    fusion_loss_kernel<<<grid, block, 0, stream>>>(A, B, F, scheme, out);
}

// Round 9
// 134.940 us; speedup vs baseline: 1.0153x; 1.0153x over previous
//
#include <hip/hip_runtime.h>

// Problem constants (from reference: shape (32,1,512,512) fp32)
#define BATCH 32
#define H 512
#define W 512
#define N_TOT (BATCH * H * W)   // 8388608

#define GLOBAL_AS __attribute__((address_space(1)))
#define LDS_AS    __attribute__((address_space(3)))

// LDS tile: 3 images x 10 rows (8 outputs + 1 halo each side) x 512 cols.
// 61,440 B -> 2 blocks/CU. Staged with async global_load_lds DMA:
// 60 chunks of 1 KiB (64 lanes x 16 B), 15 per wave, ALL in flight at once
// with ZERO VGPR cost -- this breaks the MLP-vs-spill triangle that capped
// rounds 3-8 (any register batch >~96 floats got spilled by regalloc).
#define ROWS 10
#define SMEM_FLOATS (3 * ROWS * W)   // 15360 floats
#define NCHUNK 60                    // 60 x 256 floats (1 KiB each)

__global__ __launch_bounds__(256)
void fusion_loss_kernel(const float* __restrict__ A,
                        const float* __restrict__ B,
                        const float* __restrict__ F,
                        const int* __restrict__ scheme_arr,
                        float* __restrict__ out)
{
    __shared__ float smem[SMEM_FLOATS];
    __shared__ float red[4];

    const int t    = threadIdx.x;
    const int lane = t & 63;
    const int wv   = t >> 6;
    const int b    = blockIdx.x >> 6;          // batch image
    const int band = blockIdx.x & 63;          // 64 bands of 8 rows
    const int y0   = band << 3;
    const int base = b * (H * W);
    const int scheme = scheme_arr[b];

    // ---- stage: 15 async DMA chunks per wave (chunk c -> LDS byte c*1024).
    //      chunk c: image c/20, row (c%20)>>1, half (c%20)&1. Row y = y0-1+row;
    //      OOB rows (top/bottom image edge) are zero-filled via ds_write,
    //      matching the reference's zero padding. ----
#pragma unroll
    for (int i = 0; i < 15; ++i) {
        const int c   = wv * 15 + i;
        const int im  = c / 20;
        const int rr2 = c % 20;
        const int r   = rr2 >> 1;
        const int hf  = rr2 & 1;
        const int y   = y0 - 1 + r;
        const float* img = (im == 0) ? A : (im == 1) ? B : F;
        if ((unsigned)y < (unsigned)H) {          // wave-uniform per chunk
            const float* g = img + base + y * W + (hf << 8) + (lane << 2);
            __builtin_amdgcn_global_load_lds((const GLOBAL_AS void*)g,
                                             (LDS_AS void*)(smem + c * 256),
                                             16, 0, 0);
        } else {
            *reinterpret_cast<float4*>(smem + c * 256 + (lane << 2)) =
                make_float4(0.f, 0.f, 0.f, 0.f);
        }
    }
    __syncthreads();   // compiler emits s_waitcnt vmcnt(0) before s_barrier

    float acc = 0.f;

    // ---- compute: one column per thread per phase (2 phases cover 512 cols).
    //      Lane stride 4 B -> 2-way LDS bank aliasing (free); neighbor-column
    //      reads are same-address broadcasts. Rolling h1/h2 over 10 rows. ----
#pragma unroll 1
    for (int ph = 0; ph < 2; ++ph) {
        const int c  = (ph << 8) + t;             // global col 0..511
        const float mL = (c > 0)     ? 1.f : 0.f;
        const float mR = (c < W - 1) ? 1.f : 0.f;
        const int cm = (c > 0)     ? c - 1 : c;   // clamped (value masked)
        const int cp = (c < W - 1) ? c + 1 : c;

        float sobM[8], vA[8], vB[8];

#pragma unroll
        for (int im = 0; im < 3; ++im) {
            const float* s = smem + im * (ROWS * W);
            float h1[ROWS], h2[ROWS];
#pragma unroll
            for (int r = 0; r < ROWS; ++r) {
                const float vl = s[r * W + cm] * mL;
                const float vc = s[r * W + c];
                const float vr = s[r * W + cp] * mR;
                h1[r] = vr - vl;                    // row conv [-1,0,1]
                h2[r] = vl + 2.f * vc + vr;         // row conv [1,2,1]
                if (r >= 1 && r <= 8) {             // center rows for l_loss
                    if (im == 0)      vA[r - 1] = vc;
                    else if (im == 1) vB[r - 1] = vc;
                    else {
                        const float ab = (scheme == 0) ? 0.5f * (vA[r - 1] + vB[r - 1])
                                       : (scheme == 1) ? fmaxf(vA[r - 1], vB[r - 1])
                                       : 0.f;
                        acc += fabsf(ab - vc);
                    }
                }
            }
#pragma unroll
            for (int r = 2; r < ROWS; ++r) {        // output rows y0..y0+7
                const float gx = h1[r - 2] + 2.f * h1[r - 1] + h1[r];
                const float gy = h2[r - 2] - h2[r];
                const float sob = fabsf(gx) + fabsf(gy);
                if (im == 0)      sobM[r - 2] = sob;
                else if (im == 1) sobM[r - 2] = fmaxf(sobM[r - 2], sob);
                else              acc += fabsf(sob - sobM[r - 2]);
            }
        }
    }

    // ---- reduction: 64-lane shuffle, cross-wave via LDS, one atomic ----
#pragma unroll
    for (int off = 32; off > 0; off >>= 1)
        acc += __shfl_down(acc, off, 64);
    if (lane == 0) red[wv] = acc;
    __syncthreads();
    if (t == 0)
        atomicAdd(out, (red[0] + red[1] + red[2] + red[3]) * (1.0f / (float)N_TOT));
}

extern "C" void kernel_launch(void* const* d_in, const int* in_sizes, int n_in,
                              void* d_out, int out_size, void* d_ws, size_t ws_size,
                              hipStream_t stream)
{
    const float* A = (const float*)d_in[0];
    const float* B = (const float*)d_in[1];
    const float* F = (const float*)d_in[2];
    const int* scheme = (const int*)d_in[3];
    float* out = (float*)d_out;

    // d_out is poisoned before every launch; zero it for the atomics.
    hipMemsetAsync(out, 0, sizeof(float), stream);

    dim3 grid(BATCH * 64);   // 2048 blocks: 64 row-bands x 32 batch images
    dim3 block(256);
    fusion_loss_kernel<<<grid, block, 0, stream>>>(A, B, F, scheme, out);
}